// Round 4
// baseline (263.291 us; speedup 1.0000x reference)
//
#include <hip/hip_runtime.h>
#include <stdint.h>

// occupancy_generation (DeepMapping2D):
//   out[b, j] = 1.0 if j < min(M_b, 5120) else 0.0
//   M_b = #bins with count >= 53; histogram over idx = rn(1000x)*1024 + rn(1000z)
//
// R1: scattered global atomics (646 us). R2/R3: region bucket-sort + LDS hist (221).
// R4 FAILED: fence-fused output (+90 us, XCD L2 writeback storm).
// R5/R6: split kernels, 219.4 us. Fills (512MiB 0xAA poison) = 78 us each, in dur.
// R7: 8192 pts/block + load hoist: 220.6 (= noise) -> occupancy/fixed costs don't
//     matter; time ~ per-point LDS work.
// R8 REGRESSED (239.3): parity-split cursors gained ZERO (H2 same-address
//     serialization refuted); fixed-slot hist halved lane density in the atomic
//     loop (~+10); fill itself 8 us slower on that container.
// R9 (THIS ROUND): DIAGNOSTIC. Two predictions missed in a row and neither
//     kernel has ever appeared in top-5 -> no direct counters exist. Revert to
//     R7 structure and wrap each kernel's core phase in an internal x3 repeat
//     (LDS state reset per rep; final state identical; output exact). Each
//     dispatch then exceeds the ~80 us fill cutoff and exposes dur / VALUBusy /
//     SQ_LDS_BANK_CONFLICT per kernel. dur_us will be ~2x worse BY DESIGN;
//     best-known kernel remains R7 @ 220.6. Next round acts on the counters.

static constexpr int kB        = 64;
static constexpr int kN        = 262144;    // points per cloud
static constexpr int kTopK     = 5120;
static constexpr int kRegions  = 64;        // idx>>14 == xi>>4; xi<=1000 -> region<=62
static constexpr int kCap      = 6144;      // global bucket cap; mean ~4096, +30 sigma
static constexpr int kSlots    = 256;       // per-block per-region cap; mean ~128, +11 sigma
static constexpr int kStride   = 257;       // staging stride (pad +1 breaks bank lockstep)
static constexpr int kThreads  = 256;
static constexpr int kPtsPerBlock = 8192;   // 32 points/thread, 32 blocks/cloud
static constexpr int kBlocksPerCloud = kN / kPtsPerBlock;  // 32
static constexpr int kDiagRep  = 3;         // DIAGNOSTIC repeat factor
static constexpr unsigned kThresh = 53;

// ws layout:
//   [0     ,16384) : gcnt[4096] u32 (per (cloud,region) bucket cursors)
//   [16384 ,16640) : occ[64]    u32 (per-cloud occupied-bin counts)
//   [32768 , ... ) : bdata[4096][kCap] u16 (bin-within-region values)

__global__ void __launch_bounds__(kThreads) bucketize_kernel(
    const float4* __restrict__ pcd4, uint32_t* __restrict__ gcnt,
    uint16_t* __restrict__ bdata) {
    __shared__ uint32_t s_off[kRegions];          // placement cursors
    __shared__ uint32_t s_gbase[kRegions];
    __shared__ uint32_t s_cl[kRegions];
    __shared__ uint16_t s_stage[kRegions * kStride];  // 32.9 KB

    const int tid   = threadIdx.x;
    const int bid   = blockIdx.x;
    const int cloud = bid >> 5;                   // 32 blocks per cloud
    const int batch = bid & (kBlocksPerCloud - 1);
    const size_t f4base = (size_t)cloud * (kN / 2) + (size_t)batch * (kPtsPerBlock / 2);

    // DIAG x3: repeat load->quantize->place; reset cursors each rep so the
    // final rep's state (and thus all output) is identical to single-pass.
    for (int rep = 0; rep < kDiagRep; ++rep) {
        if (tid < kRegions) s_off[tid] = 0;
        __syncthreads();
        asm volatile("" ::: "memory");  // force re-load each rep
        for (int c = 0; c < 4; ++c) {
            float4 v[4];
#pragma unroll
            for (int j = 0; j < 4; ++j)
                v[j] = pcd4[f4base + (size_t)(c * 4 + j) * kThreads + tid];
#pragma unroll
            for (int j = 0; j < 4; ++j) {
                // jnp.round == round-half-to-even -> __float2int_rn
                int i0 = __float2int_rn(1000.0f * v[j].x) * 1024 + __float2int_rn(1000.0f * v[j].y);
                int i1 = __float2int_rn(1000.0f * v[j].z) * 1024 + __float2int_rn(1000.0f * v[j].w);
                uint32_t r0 = (uint32_t)i0 >> 14, b0 = (uint32_t)i0 & 16383u;
                uint32_t r1 = (uint32_t)i1 >> 14, b1 = (uint32_t)i1 & 16383u;
                uint32_t p0 = atomicAdd(&s_off[r0], 1u);
                if (p0 < (uint32_t)kSlots) s_stage[r0 * kStride + p0] = (uint16_t)b0;
                uint32_t p1 = atomicAdd(&s_off[r1], 1u);
                if (p1 < (uint32_t)kSlots) s_stage[r1 * kStride + p1] = (uint16_t)b1;
            }
        }
        __syncthreads();
    }

    if (tid < kRegions) {  // wave 0: reserve global ranges, 64 atomics/block
        uint32_t c = s_off[tid];
        if (c > (uint32_t)kSlots) c = (uint32_t)kSlots;
        s_cl[tid] = c;
        s_gbase[tid] = atomicAdd(&gcnt[cloud * kRegions + tid], c);
    }
    __syncthreads();

    // Flush: lane-consecutive slots within a region chunk -> consecutive global
    // addresses, coalesced.
    for (int j = 0; j < kRegions * kSlots / kThreads; ++j) {
        int i = j * kThreads + tid;
        uint32_t r = (uint32_t)i >> 8;
        uint32_t off = (uint32_t)i & (kSlots - 1);
        uint32_t goff = s_gbase[r] + off;
        if (off < s_cl[r] && goff < (uint32_t)kCap)
            bdata[(size_t)(cloud * kRegions + r) * kCap + goff] = s_stage[r * kStride + off];
    }
}

__global__ void __launch_bounds__(kThreads) region_hist_kernel(
    const uint32_t* __restrict__ gcnt, const uint16_t* __restrict__ bdata,
    uint32_t* __restrict__ occ) {
    // u16-packed counters: 16384 bins in 8192 u32 = 32 KB. A bin's count is
    // bounded by the bucket count (<= kCap = 6144 < 65536): no overflow, no
    // cross-halfword carry, for ANY input.
    __shared__ uint32_t hist[8192];
    const int tid = threadIdx.x;
    const int bid = blockIdx.x;  // cloud*64 + region

    uint4* h4 = (uint4*)hist;
    uint32_t count = gcnt[bid];
    if (count > (uint32_t)kCap) count = (uint32_t)kCap;
    const uint16_t* src = bdata + (size_t)bid * kCap;
    const uint4* src4 = (const uint4*)src;     // bucket base is 16B-aligned
    const uint32_t groups = count >> 3;        // 8 u16 per uint4

    // DIAG x3: re-zero + re-accumulate; final rep's hist identical to single-pass.
    for (int rep = 0; rep < kDiagRep; ++rep) {
        for (int i = tid; i < 8192 / 4; i += kThreads) h4[i] = make_uint4(0, 0, 0, 0);
        __syncthreads();
        for (uint32_t g = tid; g < groups; g += kThreads) {
            uint4 v = src4[g];
            uint32_t w;
            w = v.x; atomicAdd(&hist[(w & 0xFFFFu) >> 1], 1u << (16u * (w & 1u)));
                     w >>= 16; atomicAdd(&hist[w >> 1], 1u << (16u * (w & 1u)));
            w = v.y; atomicAdd(&hist[(w & 0xFFFFu) >> 1], 1u << (16u * (w & 1u)));
                     w >>= 16; atomicAdd(&hist[w >> 1], 1u << (16u * (w & 1u)));
            w = v.z; atomicAdd(&hist[(w & 0xFFFFu) >> 1], 1u << (16u * (w & 1u)));
                     w >>= 16; atomicAdd(&hist[w >> 1], 1u << (16u * (w & 1u)));
            w = v.w; atomicAdd(&hist[(w & 0xFFFFu) >> 1], 1u << (16u * (w & 1u)));
                     w >>= 16; atomicAdd(&hist[w >> 1], 1u << (16u * (w & 1u)));
        }
        const uint32_t tail = groups << 3;
        if (tid < count - tail) {
            uint32_t b = src[tail + tid];
            atomicAdd(&hist[b >> 1], 1u << (16u * (b & 1u)));
        }
        __syncthreads();
    }

    uint32_t local = 0;
    for (int i = tid; i < 8192 / 4; i += kThreads) {
        uint4 v = h4[i];
        local += ((v.x & 0xFFFFu) >= kThresh) + ((v.x >> 16) >= kThresh);
        local += ((v.y & 0xFFFFu) >= kThresh) + ((v.y >> 16) >= kThresh);
        local += ((v.z & 0xFFFFu) >= kThresh) + ((v.z >> 16) >= kThresh);
        local += ((v.w & 0xFFFFu) >= kThresh) + ((v.w >> 16) >= kThresh);
    }
#pragma unroll
    for (int d = 32; d; d >>= 1) local += __shfl_down(local, d, 64);
    if ((tid & 63) == 0 && local)
        atomicAdd(&occ[bid >> 6], local);  // <=4 global atomics per block
}

__global__ void __launch_bounds__(kThreads) out_kernel(const uint32_t* __restrict__ occ,
                                                       float* __restrict__ out) {
    // 64 blocks; block b writes cloud b's 5120-float row with float4 stores.
    const int b = blockIdx.x;
    const uint32_t m = occ[b];
    const uint32_t cut = m < (uint32_t)kTopK ? m : (uint32_t)kTopK;
    float4* row = (float4*)(out + (size_t)b * kTopK);
    for (int i = threadIdx.x; i < kTopK / 4; i += kThreads) {
        uint32_t j = (uint32_t)i * 4u;
        row[i] = make_float4(j < cut ? 1.0f : 0.0f, j + 1 < cut ? 1.0f : 0.0f,
                             j + 2 < cut ? 1.0f : 0.0f, j + 3 < cut ? 1.0f : 0.0f);
    }
}

extern "C" void kernel_launch(void* const* d_in, const int* in_sizes, int n_in,
                              void* d_out, int out_size, void* d_ws, size_t ws_size,
                              hipStream_t stream) {
    const float4* pcd4 = (const float4*)d_in[0];
    float* out = (float*)d_out;

    uint32_t* gcnt  = (uint32_t*)d_ws;
    uint32_t* occ   = (uint32_t*)((char*)d_ws + 16384);
    uint16_t* bdata = (uint16_t*)((char*)d_ws + 32768);

    // Zero only the counters (ws re-poisoned to 0xAA each call).
    hipMemsetAsync(d_ws, 0, 32768, stream);

    // 64 clouds x 32 batches, 8192 points per block
    bucketize_kernel<<<kB * kBlocksPerCloud, kThreads, 0, stream>>>(pcd4, gcnt, bdata);

    // one block per (cloud, region)
    region_hist_kernel<<<kB * kRegions, kThreads, 0, stream>>>(gcnt, bdata, occ);

    // one block per cloud
    out_kernel<<<kB, kThreads, 0, stream>>>(occ, out);
}

// Round 5
// 218.706 us; speedup vs baseline: 1.2039x; 1.2039x over previous
//
#include <hip/hip_runtime.h>
#include <stdint.h>

// occupancy_generation (DeepMapping2D):
//   out[b, j] = 1.0 if j < min(M_b, 5120) else 0.0
//   M_b = #bins with count >= 53; histogram over idx = rn(1000x)*1024 + rn(1000z)
//
// R1: scattered global atomics (646). R2/R3: region bucket-sort + LDS hist (221).
// R4 FAILED: fence-fused output (+90, XCD L2 writeback storm).
// R5/R6: split kernels, 219.4. Timed iter includes one 512MiB 0xAA poison fill
//        (78 us @ 86% HBM peak) -> controllable ~142 us.
// R7: 8192 pts/block + hoist: 220.6 (null). R8 REGRESSED 239.3: parity-split
//     cursors gained ZERO (same-address serialization refuted).
// R9 DIAG (x3 core repeat): bucketize x3 = 98.5 us @ VALUBusy 21%, HBM 30%,
//     conflicts 7.5M, occupancy 38% -> no pipe saturated. Total delta vs R7:
//     +42.7 for 2 extra reps of BOTH cores -> single-pass core work (loads +
//     quantize + all LDS atomics) is only ~21 us. The other ~110 us of kernel
//     time is FIXED: launch ramp (2048+4096+64 blocks @ ~80-100 blocks/us
//     ~ 65 us) + flush/reserve (~35) . Per-point atomic theory REFUTED.
// R10 (this): persistent blocks. 1024 blocks per kernel (4/CU, co-resident),
//     bucketize loops 2 batch-tiles, hist loops 4 (cloud,region) pairs.
//     Core/LDS/flush semantics unchanged. Predict 220.6 -> 170-190.

static constexpr int kB        = 64;
static constexpr int kN        = 262144;    // points per cloud
static constexpr int kTopK     = 5120;
static constexpr int kRegions  = 64;        // idx>>14 == xi>>4; xi<=1000 -> region<=62
static constexpr int kCap      = 6144;      // global bucket cap; mean ~4096, +32 sigma
static constexpr int kSlots    = 256;       // per-tile per-region cap; mean ~128, +11 sigma
static constexpr int kStride   = 257;       // staging stride (pad +1 breaks bank lockstep)
static constexpr int kThreads  = 256;
static constexpr int kPtsPerBlock = 8192;   // points per batch-tile
static constexpr int kTilesPerCloud = kN / kPtsPerBlock;   // 32
static constexpr int kBlocksA  = 1024;      // persistent bucketize blocks (4/CU)
static constexpr int kItersA   = kB * kTilesPerCloud / kBlocksA;   // 2
static constexpr int kBlocksB  = 1024;      // persistent hist blocks (4/CU)
static constexpr int kItersB   = kB * kRegions / kBlocksB;         // 4
static constexpr unsigned kThresh = 53;

// ws layout:
//   [0     ,16384) : gcnt[4096] u32 (per (cloud,region) bucket cursors)
//   [16384 ,16640) : occ[64]    u32 (per-cloud occupied-bin counts)
//   [32768 , ... ) : bdata[4096][kCap] u16 (bin-within-region values)

__global__ void __launch_bounds__(kThreads) bucketize_kernel(
    const float4* __restrict__ pcd4, uint32_t* __restrict__ gcnt,
    uint16_t* __restrict__ bdata) {
    __shared__ uint32_t s_off[kRegions];          // placement cursors
    __shared__ uint32_t s_gbase[kRegions];
    __shared__ uint32_t s_cl[kRegions];
    __shared__ uint16_t s_stage[kRegions * kStride];  // 32.9 KB

    const int tid = threadIdx.x;

    for (int it = 0; it < kItersA; ++it) {
        const int tile  = (int)blockIdx.x + it * kBlocksA;   // 0..2047
        const int cloud = tile >> 5;
        const int batch = tile & (kTilesPerCloud - 1);
        const size_t f4base =
            (size_t)cloud * (kN / 2) + (size_t)batch * (kPtsPerBlock / 2);

        if (tid < kRegions) s_off[tid] = 0;
        __syncthreads();   // also protects s_stage reuse across iterations

        // load -> quantize -> place into fixed-stride region chunk
        for (int c = 0; c < 4; ++c) {
            float4 v[4];
#pragma unroll
            for (int j = 0; j < 4; ++j)
                v[j] = pcd4[f4base + (size_t)(c * 4 + j) * kThreads + tid];
#pragma unroll
            for (int j = 0; j < 4; ++j) {
                // jnp.round == round-half-to-even -> __float2int_rn
                int i0 = __float2int_rn(1000.0f * v[j].x) * 1024 + __float2int_rn(1000.0f * v[j].y);
                int i1 = __float2int_rn(1000.0f * v[j].z) * 1024 + __float2int_rn(1000.0f * v[j].w);
                uint32_t r0 = (uint32_t)i0 >> 14, b0 = (uint32_t)i0 & 16383u;
                uint32_t r1 = (uint32_t)i1 >> 14, b1 = (uint32_t)i1 & 16383u;
                uint32_t p0 = atomicAdd(&s_off[r0], 1u);
                if (p0 < (uint32_t)kSlots) s_stage[r0 * kStride + p0] = (uint16_t)b0;
                uint32_t p1 = atomicAdd(&s_off[r1], 1u);
                if (p1 < (uint32_t)kSlots) s_stage[r1 * kStride + p1] = (uint16_t)b1;
            }
        }
        __syncthreads();

        if (tid < kRegions) {  // reserve global ranges: 64 atomics per tile
            uint32_t c = s_off[tid];
            if (c > (uint32_t)kSlots) c = (uint32_t)kSlots;
            s_cl[tid] = c;
            s_gbase[tid] = atomicAdd(&gcnt[cloud * kRegions + tid], c);
        }
        __syncthreads();

        // Flush: lane-consecutive slots -> consecutive global addresses.
        for (int j = 0; j < kRegions * kSlots / kThreads; ++j) {
            int i = j * kThreads + tid;
            uint32_t r = (uint32_t)i >> 8;
            uint32_t off = (uint32_t)i & (kSlots - 1);
            uint32_t goff = s_gbase[r] + off;
            if (off < s_cl[r] && goff < (uint32_t)kCap)
                bdata[(size_t)(cloud * kRegions + r) * kCap + goff] = s_stage[r * kStride + off];
        }
        __syncthreads();   // flush reads s_stage; next iter overwrites it
    }
}

__global__ void __launch_bounds__(kThreads) region_hist_kernel(
    const uint32_t* __restrict__ gcnt, const uint16_t* __restrict__ bdata,
    uint32_t* __restrict__ occ) {
    // u16-packed counters: 16384 bins in 8192 u32 = 32 KB. A bin's count is
    // bounded by the bucket count (<= kCap = 6144 < 65536): no overflow, no
    // cross-halfword carry, for ANY input.
    __shared__ uint32_t hist[8192];
    const int tid = threadIdx.x;
    uint4* h4 = (uint4*)hist;

    for (int it = 0; it < kItersB; ++it) {
        const int pair = (int)blockIdx.x + it * kBlocksB;  // cloud*64 + region

        for (int i = tid; i < 8192 / 4; i += kThreads) h4[i] = make_uint4(0, 0, 0, 0);
        __syncthreads();

        uint32_t count = gcnt[pair];
        if (count > (uint32_t)kCap) count = (uint32_t)kCap;
        const uint16_t* src = bdata + (size_t)pair * kCap;
        const uint4* src4 = (const uint4*)src;     // bucket base is 16B-aligned
        const uint32_t groups = count >> 3;        // 8 u16 per uint4
        for (uint32_t g = tid; g < groups; g += kThreads) {
            uint4 v = src4[g];
            uint32_t w;
            w = v.x; atomicAdd(&hist[(w & 0xFFFFu) >> 1], 1u << (16u * (w & 1u)));
                     w >>= 16; atomicAdd(&hist[w >> 1], 1u << (16u * (w & 1u)));
            w = v.y; atomicAdd(&hist[(w & 0xFFFFu) >> 1], 1u << (16u * (w & 1u)));
                     w >>= 16; atomicAdd(&hist[w >> 1], 1u << (16u * (w & 1u)));
            w = v.z; atomicAdd(&hist[(w & 0xFFFFu) >> 1], 1u << (16u * (w & 1u)));
                     w >>= 16; atomicAdd(&hist[w >> 1], 1u << (16u * (w & 1u)));
            w = v.w; atomicAdd(&hist[(w & 0xFFFFu) >> 1], 1u << (16u * (w & 1u)));
                     w >>= 16; atomicAdd(&hist[w >> 1], 1u << (16u * (w & 1u)));
        }
        const uint32_t tail = groups << 3;
        if (tid < count - tail) {
            uint32_t b = src[tail + tid];
            atomicAdd(&hist[b >> 1], 1u << (16u * (b & 1u)));
        }
        __syncthreads();

        uint32_t local = 0;
        for (int i = tid; i < 8192 / 4; i += kThreads) {
            uint4 v = h4[i];
            local += ((v.x & 0xFFFFu) >= kThresh) + ((v.x >> 16) >= kThresh);
            local += ((v.y & 0xFFFFu) >= kThresh) + ((v.y >> 16) >= kThresh);
            local += ((v.z & 0xFFFFu) >= kThresh) + ((v.z >> 16) >= kThresh);
            local += ((v.w & 0xFFFFu) >= kThresh) + ((v.w >> 16) >= kThresh);
        }
#pragma unroll
        for (int d = 32; d; d >>= 1) local += __shfl_down(local, d, 64);
        if ((tid & 63) == 0 && local)
            atomicAdd(&occ[pair >> 6], local);  // <=4 global atomics per pair
        __syncthreads();   // sweep reads hist; next iter re-zeroes it
    }
}

__global__ void __launch_bounds__(kThreads) out_kernel(const uint32_t* __restrict__ occ,
                                                       float* __restrict__ out) {
    // 64 blocks; block b writes cloud b's 5120-float row with float4 stores.
    const int b = blockIdx.x;
    const uint32_t m = occ[b];
    const uint32_t cut = m < (uint32_t)kTopK ? m : (uint32_t)kTopK;
    float4* row = (float4*)(out + (size_t)b * kTopK);
    for (int i = threadIdx.x; i < kTopK / 4; i += kThreads) {
        uint32_t j = (uint32_t)i * 4u;
        row[i] = make_float4(j < cut ? 1.0f : 0.0f, j + 1 < cut ? 1.0f : 0.0f,
                             j + 2 < cut ? 1.0f : 0.0f, j + 3 < cut ? 1.0f : 0.0f);
    }
}

extern "C" void kernel_launch(void* const* d_in, const int* in_sizes, int n_in,
                              void* d_out, int out_size, void* d_ws, size_t ws_size,
                              hipStream_t stream) {
    const float4* pcd4 = (const float4*)d_in[0];
    float* out = (float*)d_out;

    uint32_t* gcnt  = (uint32_t*)d_ws;
    uint32_t* occ   = (uint32_t*)((char*)d_ws + 16384);
    uint16_t* bdata = (uint16_t*)((char*)d_ws + 32768);

    // Zero only the counters (ws re-poisoned to 0xAA each call).
    hipMemsetAsync(d_ws, 0, 32768, stream);

    // persistent: 1024 blocks x 2 batch-tiles
    bucketize_kernel<<<kBlocksA, kThreads, 0, stream>>>(pcd4, gcnt, bdata);

    // persistent: 1024 blocks x 4 (cloud, region) pairs
    region_hist_kernel<<<kBlocksB, kThreads, 0, stream>>>(gcnt, bdata, occ);

    // one block per cloud
    out_kernel<<<kB, kThreads, 0, stream>>>(occ, out);
}

// Round 6
// 217.984 us; speedup vs baseline: 1.2078x; 1.0033x over previous
//
#include <hip/hip_runtime.h>
#include <stdint.h>

// occupancy_generation (DeepMapping2D):
//   out[b, j] = 1.0 if j < min(M_b, 5120) else 0.0
//   M_b = #bins with count >= 53; histogram over idx = rn(1000x)*1024 + rn(1000z)
//
// R1 global atomics: 646. R2/R3 region bucket-sort + LDS hist: 221.
// R4 FAILED fence-fusion (+90, XCD L2 storm). R5/R6: 219.4 (fill 78 us of it).
// R7 (8K pts/blk): null. R8 (parity cursors, fixed slots): REGRESSED 239
//     (half-masked hist groups). R9 DIAG x3: cores (loads+quantize+ALL LDS
//     atomics) = only ~21 us single-pass; bucketize x3 = 98.5 @ VALU 21%,
//     HBM 30%, 38% occ -> nothing saturated. R10 persistent 1024-blocks: null
//     (218.7) -> launch ramp refuted.
// => The ~40-57 us hidden cost in bucketize must be the un-repeated epilogue:
//    128 scalar latency-exposed memory insts/thread (64x masked u16 LDS read +
//    64x masked u16 global store) + masked hist tail.
// R11 (this): EXACT padded segments. Reserve per-tile per-region space rounded
//    up to 8 u16 (pads = region bin 0; dual cursors gcnt_pad/gcnt_true; hist
//    subtracts pad from bin0 count -> exact for ANY input). Flush becomes
//    8 x ds_read_b128 + dense uint4 stores (16x fewer mem insts); hist groups
//    fully dense, tail eliminated. Predict 185-205 if epilogue theory right.

static constexpr int kB        = 64;
static constexpr int kN        = 262144;    // points per cloud
static constexpr int kTopK     = 5120;
static constexpr int kRegions  = 64;        // idx>>14 == xi>>4; xi<=1000 -> region<=62
static constexpr int kCap      = 6144;      // u16 slots per (cloud,region); mult of 8; +25 sigma
static constexpr int kSlots    = 256;       // per-tile per-region LDS cap; mean ~128, +11 sigma
static constexpr int kStrideU16= 264;       // u16 stride per region chunk (528 B, 16B-aligned)
static constexpr int kThreads  = 256;
static constexpr int kPtsPerTile = 8192;    // 32 points/thread
static constexpr int kTilesPerCloud = kN / kPtsPerTile;          // 32
static constexpr int kBlocksA  = 1024;      // persistent bucketize blocks (4/CU)
static constexpr int kItersA   = kB * kTilesPerCloud / kBlocksA; // 2
static constexpr int kBlocksB  = 1024;      // persistent hist blocks
static constexpr int kItersB   = kB * kRegions / kBlocksB;       // 4
static constexpr unsigned kThresh = 53;

// ws layout:
//   [0     ,16384) : gcnt_pad[4096]  u32  (padded cursors; placement offsets)
//   [16384 ,32768) : gcnt_true[4096] u32  (true entry counts)
//   [32768 ,33024) : occ[64]         u32  (per-cloud occupied-bin counts)
//   [65536 , ... ) : bdata[4096][kCap] u16 (segments; 16B-aligned, 8-u16 padded)

__global__ void __launch_bounds__(kThreads) bucketize_kernel(
    const float4* __restrict__ pcd4, uint32_t* __restrict__ gcnt_pad,
    uint32_t* __restrict__ gcnt_true, uint16_t* __restrict__ bdata) {
    __shared__ uint4    s_stage4[kRegions * (kStrideU16 / 8)];  // 33792 B, 16B-aligned
    __shared__ uint32_t s_off[kRegions];
    __shared__ uint32_t s_gbase[kRegions];
    __shared__ uint32_t s_cl[kRegions];     // padded count per region (mult of 8)
    uint16_t* s_stage = (uint16_t*)s_stage4;

    const int tid = threadIdx.x;

    for (int it = 0; it < kItersA; ++it) {
        const int tile  = (int)blockIdx.x + it * kBlocksA;   // 0..2047
        const int cloud = tile >> 5;
        const int batch = tile & (kTilesPerCloud - 1);
        const size_t f4base =
            (size_t)cloud * (kN / 2) + (size_t)batch * (kPtsPerTile / 2);

        if (tid < kRegions) s_off[tid] = 0;
        __syncthreads();

        // load -> quantize -> place into fixed-stride region chunk
        for (int c = 0; c < 4; ++c) {
            float4 v[4];
#pragma unroll
            for (int j = 0; j < 4; ++j)
                v[j] = pcd4[f4base + (size_t)(c * 4 + j) * kThreads + tid];
#pragma unroll
            for (int j = 0; j < 4; ++j) {
                // jnp.round == round-half-to-even -> __float2int_rn
                int i0 = __float2int_rn(1000.0f * v[j].x) * 1024 + __float2int_rn(1000.0f * v[j].y);
                int i1 = __float2int_rn(1000.0f * v[j].z) * 1024 + __float2int_rn(1000.0f * v[j].w);
                uint32_t r0 = (uint32_t)i0 >> 14, b0 = (uint32_t)i0 & 16383u;
                uint32_t r1 = (uint32_t)i1 >> 14, b1 = (uint32_t)i1 & 16383u;
                uint32_t p0 = atomicAdd(&s_off[r0], 1u);
                if (p0 < (uint32_t)kSlots) s_stage[r0 * kStrideU16 + p0] = (uint16_t)b0;
                uint32_t p1 = atomicAdd(&s_off[r1], 1u);
                if (p1 < (uint32_t)kSlots) s_stage[r1 * kStrideU16 + p1] = (uint16_t)b1;
            }
        }
        __syncthreads();

        if (tid < kRegions) {   // reserve padded range; pads = bin 0 of region
            uint32_t c = s_off[tid];
            if (c > (uint32_t)kSlots) c = (uint32_t)kSlots;
            uint32_t cp = (c + 7u) & ~7u;               // <= kSlots (256 = 32*8)
            for (uint32_t k = c; k < cp; ++k) s_stage[tid * kStrideU16 + k] = 0;
            s_cl[tid] = cp;
            s_gbase[tid] = atomicAdd(&gcnt_pad[cloud * kRegions + tid], cp);
            atomicAdd(&gcnt_true[cloud * kRegions + tid], c);
        }
        __syncthreads();

        // Flush: 64 regions x 32 chunks of 16B = 2048 chunks / 256 thr = 8 iters.
        // All-vector: ds_read_b128 + uint4 global store, dense within padded count.
        for (int j = 0; j < kRegions * kSlots / 8 / kThreads; ++j) {  // 8
            int i = j * kThreads + tid;
            uint32_t r = (uint32_t)i >> 5;
            uint32_t o = ((uint32_t)i & 31u) << 3;       // u16 offset, mult of 8
            uint32_t gb = s_gbase[r];
            if (o < s_cl[r] && gb + o + 8u <= (uint32_t)kCap) {
                uint4 v = s_stage4[r * (kStrideU16 / 8) + (o >> 3)];
                *(uint4*)&bdata[(((size_t)cloud * kRegions + r) * kCap) + gb + o] = v;
            }
        }
        __syncthreads();   // s_stage/s_gbase reused next iteration
    }
}

__global__ void __launch_bounds__(kThreads) region_hist_kernel(
    const uint32_t* __restrict__ gcnt_pad, const uint32_t* __restrict__ gcnt_true,
    const uint16_t* __restrict__ bdata, uint32_t* __restrict__ occ) {
    // u16-packed counters: 16384 bins in 8192 u32 = 32 KB. A bin's count is
    // bounded by processed entries (<= kCap = 6144 < 65536): no overflow.
    __shared__ uint32_t hist[8192];
    const int tid = threadIdx.x;
    uint4* h4 = (uint4*)hist;

    for (int it = 0; it < kItersB; ++it) {
        const int pair = (int)blockIdx.x + it * kBlocksB;  // cloud*64 + region

        for (int i = tid; i < 8192 / 4; i += kThreads) h4[i] = make_uint4(0, 0, 0, 0);
        __syncthreads();

        uint32_t cnt = gcnt_pad[pair];
        if (cnt > (uint32_t)kCap) cnt = (uint32_t)kCap;   // kCap mult of 8
        const uint4* src4 = (const uint4*)(bdata + (size_t)pair * kCap);
        const uint32_t groups = cnt >> 3;                  // DENSE: no masking, no tail
        for (uint32_t g = tid; g < groups; g += kThreads) {
            uint4 v = src4[g];
            uint32_t w;
            w = v.x; atomicAdd(&hist[(w & 0xFFFFu) >> 1], 1u << (16u * (w & 1u)));
                     w >>= 16; atomicAdd(&hist[w >> 1], 1u << (16u * (w & 1u)));
            w = v.y; atomicAdd(&hist[(w & 0xFFFFu) >> 1], 1u << (16u * (w & 1u)));
                     w >>= 16; atomicAdd(&hist[w >> 1], 1u << (16u * (w & 1u)));
            w = v.z; atomicAdd(&hist[(w & 0xFFFFu) >> 1], 1u << (16u * (w & 1u)));
                     w >>= 16; atomicAdd(&hist[w >> 1], 1u << (16u * (w & 1u)));
            w = v.w; atomicAdd(&hist[(w & 0xFFFFu) >> 1], 1u << (16u * (w & 1u)));
                     w >>= 16; atomicAdd(&hist[w >> 1], 1u << (16u * (w & 1u)));
        }
        __syncthreads();

        if (tid == 0) {   // remove pad entries (all were bin 0 -> hist[0] low16)
            uint32_t pad = gcnt_pad[pair] - gcnt_true[pair];
            uint32_t lo = hist[0] & 0xFFFFu;
            if (pad > lo) pad = lo;    // only reachable in astronomically-rare cap overflow
            hist[0] -= pad;
        }
        __syncthreads();

        uint32_t local = 0;
        for (int i = tid; i < 8192 / 4; i += kThreads) {
            uint4 v = h4[i];
            local += ((v.x & 0xFFFFu) >= kThresh) + ((v.x >> 16) >= kThresh);
            local += ((v.y & 0xFFFFu) >= kThresh) + ((v.y >> 16) >= kThresh);
            local += ((v.z & 0xFFFFu) >= kThresh) + ((v.z >> 16) >= kThresh);
            local += ((v.w & 0xFFFFu) >= kThresh) + ((v.w >> 16) >= kThresh);
        }
#pragma unroll
        for (int d = 32; d; d >>= 1) local += __shfl_down(local, d, 64);
        if ((tid & 63) == 0 && local)
            atomicAdd(&occ[pair >> 6], local);  // <=4 global atomics per pair
        __syncthreads();   // hist reused next iteration
    }
}

__global__ void __launch_bounds__(kThreads) out_kernel(const uint32_t* __restrict__ occ,
                                                       float* __restrict__ out) {
    // 64 blocks; block b writes cloud b's 5120-float row with float4 stores.
    const int b = blockIdx.x;
    const uint32_t m = occ[b];
    const uint32_t cut = m < (uint32_t)kTopK ? m : (uint32_t)kTopK;
    float4* row = (float4*)(out + (size_t)b * kTopK);
    for (int i = threadIdx.x; i < kTopK / 4; i += kThreads) {
        uint32_t j = (uint32_t)i * 4u;
        row[i] = make_float4(j < cut ? 1.0f : 0.0f, j + 1 < cut ? 1.0f : 0.0f,
                             j + 2 < cut ? 1.0f : 0.0f, j + 3 < cut ? 1.0f : 0.0f);
    }
}

extern "C" void kernel_launch(void* const* d_in, const int* in_sizes, int n_in,
                              void* d_out, int out_size, void* d_ws, size_t ws_size,
                              hipStream_t stream) {
    const float4* pcd4 = (const float4*)d_in[0];
    float* out = (float*)d_out;

    uint32_t* gcnt_pad  = (uint32_t*)d_ws;                       // 16 KB
    uint32_t* gcnt_true = (uint32_t*)((char*)d_ws + 16384);      // 16 KB
    uint32_t* occ       = (uint32_t*)((char*)d_ws + 32768);      // 256 B
    uint16_t* bdata     = (uint16_t*)((char*)d_ws + 65536);      // 50.3 MB

    // Zero only the cursors/counters (ws re-poisoned to 0xAA each call).
    hipMemsetAsync(d_ws, 0, 33024, stream);

    // persistent: 1024 blocks x 2 batch-tiles
    bucketize_kernel<<<kBlocksA, kThreads, 0, stream>>>(pcd4, gcnt_pad, gcnt_true, bdata);

    // persistent: 1024 blocks x 4 (cloud, region) pairs
    region_hist_kernel<<<kBlocksB, kThreads, 0, stream>>>(gcnt_pad, gcnt_true, bdata, occ);

    // one block per cloud
    out_kernel<<<kB, kThreads, 0, stream>>>(occ, out);
}